// Round 1
// baseline (28546.469 us; speedup 1.0000x reference)
//
#include <hip/hip_runtime.h>

// Problem constants (fixed by the reference)
#define NN 50000
#define TT 200
#define HH 128
#define EE 1600000

typedef _Float16 f16x8 __attribute__((ext_vector_type(8)));
typedef float f32x4 __attribute__((ext_vector_type(4)));

__device__ __forceinline__ float fast_rcp(float x) { return __builtin_amdgcn_rcpf(x); }

__device__ __forceinline__ float sigf(float x) {
    x = fminf(fmaxf(x, -30.f), 30.f);
    return fast_rcp(1.f + __expf(-x));
}
__device__ __forceinline__ float tanhf_(float x) {
    float ax = fminf(fabsf(x), 15.f);
    float e = __expf(2.f * ax);
    float t = 1.f - 2.f * fast_rcp(e + 1.f);
    return (x >= 0.f) ? t : -t;
}
__device__ __forceinline__ unsigned short f2h_bits(float x) {
    _Float16 h = (_Float16)x;
    union { _Float16 h; unsigned short u; } cv; cv.h = h; return cv.u;
}

// ---------------------------------------------------------------------------
// Weight packing: W is (512,128) row-major (PyTorch [4H, H]).
// We need Wt[k][n] = W[n][k] packed in MFMA-16x16x32 B-fragment order:
// tile (jn in 0..31, kk in 0..3), lane L holds Wt[kk*32 + (L>>4)*8 + i][jn*16 + (L&15)]
// stored contiguously: out[(jn*4+kk)*512 + L*8 + i]  (ushort/f16 units)
// ---------------------------------------------------------------------------
__global__ void pack_w(const float* __restrict__ W, unsigned short* __restrict__ out) {
    int tile = blockIdx.x;          // jn*4 + kk
    int jn = tile >> 2, kk = tile & 3;
    int L = threadIdx.x;            // 0..63
    int n = jn * 16 + (L & 15);
    int k0 = kk * 32 + (L >> 4) * 8;
    unsigned short* dst = out + (size_t)tile * 512 + L * 8;
#pragma unroll
    for (int i = 0; i < 8; ++i) dst[i] = f2h_bits(W[n * 128 + k0 + i]);
}

__global__ void bias_prep(const float* __restrict__ bih0, const float* __restrict__ bhh0,
                          const float* __restrict__ bih1, const float* __restrict__ bhh1,
                          const float* __restrict__ wih0,
                          float* __restrict__ b0g, float* __restrict__ b1g, float* __restrict__ wxg) {
    int i = blockIdx.x * 256 + threadIdx.x;
    if (i < 512) {
        b0g[i] = bih0[i] + bhh0[i];
        b1g[i] = bih1[i] + bhh1[i];
        wxg[i] = wih0[i];
    }
}

// lightcurve [N][T] -> xT [T][N]
__global__ void transpose_lc(const float* __restrict__ lc, float* __restrict__ xT) {
    __shared__ float tile[32][33];
    int tx = threadIdx.x, ty = threadIdx.y;    // 32 x 8
    int n0 = blockIdx.y * 32, t0 = blockIdx.x * 32;
#pragma unroll
    for (int i = 0; i < 32; i += 8) {
        int n = n0 + ty + i, t = t0 + tx;
        if (n < NN && t < TT) tile[ty + i][tx] = lc[(size_t)n * TT + t];
    }
    __syncthreads();
#pragma unroll
    for (int i = 0; i < 32; i += 8) {
        int t = t0 + ty + i, n = n0 + tx;
        if (n < NN && t < TT) xT[(size_t)t * NN + n] = tile[tx][ty + i];
    }
}

// ---------------------------------------------------------------------------
// Fused 2-layer LSTM. Block = 256 threads (4 waves), 64 nodes/block, all 200 steps.
// Wave w owns n-tiles with (tile mod 4 == w): for each gate g and q in {0,1},
// tile = 8g + w + 4q  -> all four gates for column j = (w+4q)*16 + (lane&15).
// h-states in LDS as f16 (A-fragment friendly row-major, pad 8), c-states fp32 regs.
// ---------------------------------------------------------------------------
__global__ __launch_bounds__(256, 2) void lstm_kernel(
    const float* __restrict__ xT,
    const unsigned short* __restrict__ w0p,
    const unsigned short* __restrict__ w1ip,
    const unsigned short* __restrict__ w1hp,
    const float* __restrict__ b0g, const float* __restrict__ b1g,
    const float* __restrict__ wxg,
    float* __restrict__ h2out) {
    __shared__ unsigned short h1s[64][136];
    __shared__ unsigned short h2s[64][136];
    __shared__ float xs[64];
    __shared__ float b0s[512], b1s[512], wxs[512];

    const int tid = threadIdx.x;
    const int w = tid >> 6;
    const int lane = tid & 63;
    const int col = lane & 15;
    const int quad = lane >> 4;
    const int n0 = blockIdx.x * 64;

    for (int i = tid; i < 64 * 136; i += 256) { (&h1s[0][0])[i] = 0; (&h2s[0][0])[i] = 0; }
    for (int i = tid; i < 512; i += 256) { b0s[i] = b0g[i]; b1s[i] = b1g[i]; wxs[i] = wxg[i]; }

    float c1[4][2][4] = {};
    float c2[4][2][4] = {};
    float h1r[4][2][4];
    float h2r[4][2][4];

    const int jq[2] = { w * 16 + col, (w + 4) * 16 + col };

#pragma unroll 1
    for (int t = 0; t < TT; ++t) {
        if (tid < 64) {
            int n = n0 + tid;
            xs[tid] = (n < NN) ? xT[(size_t)t * NN + n] : 0.f;
        }
        __syncthreads();   // xs + h1s/h2s (prev step) visible

        // ---------------- layer 0: g0 = h1 @ W_hh0^T + x*w_ih0 + b0
#pragma unroll
        for (int q = 0; q < 2; ++q) {
            f32x4 acc[4][4];
#pragma unroll
            for (int rt = 0; rt < 4; ++rt)
#pragma unroll
                for (int g = 0; g < 4; ++g)
#pragma unroll
                    for (int e = 0; e < 4; ++e) acc[rt][g][e] = 0.f;
#pragma unroll
            for (int kk = 0; kk < 4; ++kk) {
                f16x8 a[4];
#pragma unroll
                for (int rt = 0; rt < 4; ++rt)
                    a[rt] = *reinterpret_cast<const f16x8*>(&h1s[rt * 16 + col][kk * 32 + quad * 8]);
#pragma unroll
                for (int g = 0; g < 4; ++g) {
                    const int tile = 8 * g + w + 4 * q;
                    f16x8 b = *reinterpret_cast<const f16x8*>(w0p + (size_t)(tile * 4 + kk) * 512 + lane * 8);
#pragma unroll
                    for (int rt = 0; rt < 4; ++rt)
                        acc[rt][g] = __builtin_amdgcn_mfma_f32_16x16x32_f16(a[rt], b, acc[rt][g], 0, 0, 0);
                }
            }
            const int j = jq[q];
            const float bi = b0s[j], bf = b0s[128 + j], bgg = b0s[256 + j], bo = b0s[384 + j];
            const float wi = wxs[j], wf = wxs[128 + j], wgg = wxs[256 + j], wo = wxs[384 + j];
#pragma unroll
            for (int rt = 0; rt < 4; ++rt) {
#pragma unroll
                for (int r = 0; r < 4; ++r) {
                    const int m = rt * 16 + quad * 4 + r;
                    const float x = xs[m];
                    float gi = acc[rt][0][r] + bi + x * wi;
                    float gf = acc[rt][1][r] + bf + x * wf;
                    float gg = acc[rt][2][r] + bgg + x * wgg;
                    float go = acc[rt][3][r] + bo + x * wo;
                    float cc = sigf(gf) * c1[rt][q][r] + sigf(gi) * tanhf_(gg);
                    c1[rt][q][r] = cc;
                    h1r[rt][q][r] = sigf(go) * tanhf_(cc);
                }
            }
        }
        __syncthreads();   // everyone done reading old h1s
#pragma unroll
        for (int q = 0; q < 2; ++q)
#pragma unroll
            for (int rt = 0; rt < 4; ++rt)
#pragma unroll
                for (int r = 0; r < 4; ++r)
                    h1s[rt * 16 + quad * 4 + r][jq[q]] = f2h_bits(h1r[rt][q][r]);
        __syncthreads();   // new h1s visible

        // ---------------- layer 1: g1 = h1_new @ W_ih1^T + h2 @ W_hh1^T + b1
#pragma unroll
        for (int q = 0; q < 2; ++q) {
            f32x4 acc[4][4];
#pragma unroll
            for (int rt = 0; rt < 4; ++rt)
#pragma unroll
                for (int g = 0; g < 4; ++g)
#pragma unroll
                    for (int e = 0; e < 4; ++e) acc[rt][g][e] = 0.f;
#pragma unroll
            for (int kk = 0; kk < 8; ++kk) {
                const unsigned short (*hs)[136] = (kk < 4) ? h1s : h2s;
                const unsigned short* wp = (kk < 4) ? w1ip : w1hp;
                const int kc = kk & 3;
                f16x8 a[4];
#pragma unroll
                for (int rt = 0; rt < 4; ++rt)
                    a[rt] = *reinterpret_cast<const f16x8*>(&hs[rt * 16 + col][kc * 32 + quad * 8]);
#pragma unroll
                for (int g = 0; g < 4; ++g) {
                    const int tile = 8 * g + w + 4 * q;
                    f16x8 b = *reinterpret_cast<const f16x8*>(wp + (size_t)(tile * 4 + kc) * 512 + lane * 8);
#pragma unroll
                    for (int rt = 0; rt < 4; ++rt)
                        acc[rt][g] = __builtin_amdgcn_mfma_f32_16x16x32_f16(a[rt], b, acc[rt][g], 0, 0, 0);
                }
            }
            const int j = jq[q];
            const float bi = b1s[j], bf = b1s[128 + j], bgg = b1s[256 + j], bo = b1s[384 + j];
#pragma unroll
            for (int rt = 0; rt < 4; ++rt) {
#pragma unroll
                for (int r = 0; r < 4; ++r) {
                    float gi = acc[rt][0][r] + bi;
                    float gf = acc[rt][1][r] + bf;
                    float gg = acc[rt][2][r] + bgg;
                    float go = acc[rt][3][r] + bo;
                    float cc = sigf(gf) * c2[rt][q][r] + sigf(gi) * tanhf_(gg);
                    c2[rt][q][r] = cc;
                    h2r[rt][q][r] = sigf(go) * tanhf_(cc);
                }
            }
        }
        __syncthreads();   // everyone done reading old h2s
#pragma unroll
        for (int q = 0; q < 2; ++q)
#pragma unroll
            for (int rt = 0; rt < 4; ++rt)
#pragma unroll
                for (int r = 0; r < 4; ++r)
                    h2s[rt * 16 + quad * 4 + r][jq[q]] = f2h_bits(h2r[rt][q][r]);
    }

    // final hidden state of layer 2 -> global (fp32)
#pragma unroll
    for (int q = 0; q < 2; ++q)
#pragma unroll
        for (int rt = 0; rt < 4; ++rt)
#pragma unroll
            for (int r = 0; r < 4; ++r) {
                int m = rt * 16 + quad * 4 + r;
                int n = n0 + m;
                if (n < NN) h2out[(size_t)n * HH + jq[q]] = h2r[rt][q][r];
            }
}

// ---------------------------------------------------------------------------
// GCN pieces (fp32)
// ---------------------------------------------------------------------------
__global__ void deg_init(float* __restrict__ deg) {
    int i = blockIdx.x * 256 + threadIdx.x;
    if (i < NN) deg[i] = 1.f;   // self loop
}
__global__ void deg_edges(const int* __restrict__ ei, float* __restrict__ deg) {
    int e = blockIdx.x * 256 + threadIdx.x;
    if (e < EE) unsafeAtomicAdd(&deg[ei[EE + e]], 1.f);   // col = target
}
__global__ void dinv_k(const float* __restrict__ deg, float* __restrict__ dinv) {
    int i = blockIdx.x * 256 + threadIdx.x;
    if (i < NN) dinv[i] = rsqrtf(fmaxf(deg[i], 1.f));
}
__global__ void enorm_k(const int* __restrict__ ei, const float* __restrict__ dinv,
                        float* __restrict__ enorm) {
    int e = blockIdx.x * 256 + threadIdx.x;
    if (e < EE) enorm[e] = dinv[ei[e]] * dinv[ei[EE + e]];
}

// hw = h @ Wg   ([N,128] x [128,128]); 32 nodes per block
__global__ void gcn_gemm(const float* __restrict__ h, const float* __restrict__ Wg,
                         float* __restrict__ hw) {
    __shared__ float hsT[128][36];   // [k][m], pad to 36 for 16B-aligned rows
    int tid = threadIdx.x;
    int n0 = blockIdx.x * 32;
#pragma unroll
    for (int c = 0; c < 16; ++c) {
        int lin = c * 256 + tid;
        int m = lin >> 7, k = lin & 127;
        int n = n0 + m;
        hsT[k][m] = (n < NN) ? h[(size_t)n * HH + k] : 0.f;
    }
    __syncthreads();
    int j = tid & 127, p = tid >> 7;
    float acc[16];
#pragma unroll
    for (int m = 0; m < 16; ++m) acc[m] = 0.f;
    for (int k = 0; k < 128; ++k) {
        float wg = Wg[k * 128 + j];
        const float4* hp = reinterpret_cast<const float4*>(&hsT[k][p * 16]);
        float4 a = hp[0], b = hp[1], c = hp[2], d = hp[3];
        acc[0]  += a.x * wg; acc[1]  += a.y * wg; acc[2]  += a.z * wg; acc[3]  += a.w * wg;
        acc[4]  += b.x * wg; acc[5]  += b.y * wg; acc[6]  += b.z * wg; acc[7]  += b.w * wg;
        acc[8]  += c.x * wg; acc[9]  += c.y * wg; acc[10] += c.z * wg; acc[11] += c.w * wg;
        acc[12] += d.x * wg; acc[13] += d.y * wg; acc[14] += d.z * wg; acc[15] += d.w * wg;
    }
#pragma unroll
    for (int m = 0; m < 16; ++m) {
        int n = n0 + p * 16 + m;
        if (n < NN) hw[(size_t)n * HH + j] = acc[m];
    }
}

// hacc[v] = bg + dinv[v]^2 * hw[v]  (self-loop + bias init)
__global__ void gcn_init(const float* __restrict__ hw, const float* __restrict__ dinv,
                         const float* __restrict__ bg, float* __restrict__ hacc) {
    int idx = blockIdx.x * 256 + threadIdx.x;   // over N*32 float4 groups
    if (idx >= NN * 32) return;
    int n = idx >> 5, g = idx & 31;
    float d = dinv[n];
    float s = d * d;
    float4 v = reinterpret_cast<const float4*>(hw)[idx];
    float4 b = reinterpret_cast<const float4*>(bg)[g];
    float4 o;
    o.x = b.x + s * v.x; o.y = b.y + s * v.y; o.z = b.z + s * v.z; o.w = b.w + s * v.w;
    reinterpret_cast<float4*>(hacc)[idx] = o;
}

// scatter-add over edges: hacc[col] += enorm[e] * hw[row]; 32 threads/edge x float4
__global__ void gcn_scatter(const float* __restrict__ hw, const int* __restrict__ ei,
                            const float* __restrict__ enorm, float* __restrict__ hacc) {
    int gid = blockIdx.x * 256 + threadIdx.x;   // E*32 = 51.2e6 < 2^31
    int e = gid >> 5, s = gid & 31;
    int r = ei[e], c = ei[EE + e];
    float wv = enorm[e];
    float4 v = reinterpret_cast<const float4*>(hw)[r * 32 + s];
    float* dst = hacc + (size_t)c * HH + s * 4;
    unsafeAtomicAdd(dst + 0, wv * v.x);
    unsafeAtomicAdd(dst + 1, wv * v.y);
    unsafeAtomicAdd(dst + 2, wv * v.z);
    unsafeAtomicAdd(dst + 3, wv * v.w);
}

// LayerNorm + relu + residual; one wave per node (2 elems/thread)
__global__ void gcn_ln(const float* __restrict__ hacc, const float* __restrict__ gamma,
                       const float* __restrict__ beta, float* __restrict__ h) {
    int wv = threadIdx.x >> 6, lane = threadIdx.x & 63;
    int n = blockIdx.x * 4 + wv;
    if (n >= NN) return;
    const float* src = hacc + (size_t)n * HH;
    float a = src[lane], b = src[64 + lane];
    float s = a + b;
#pragma unroll
    for (int o = 32; o; o >>= 1) s += __shfl_xor(s, o);
    float mu = s * (1.f / 128.f);
    float da = a - mu, db = b - mu;
    float v = da * da + db * db;
#pragma unroll
    for (int o = 32; o; o >>= 1) v += __shfl_xor(v, o);
    float rn = rsqrtf(v * (1.f / 128.f) + 1e-5f);
    float o1 = da * rn * gamma[lane] + beta[lane];
    float o2 = db * rn * gamma[64 + lane] + beta[64 + lane];
    float* dst = h + (size_t)n * HH;
    dst[lane]      = fmaxf(o1, 0.f) + dst[lane];
    dst[64 + lane] = fmaxf(o2, 0.f) + dst[64 + lane];
}

__global__ void pool_k(const float* __restrict__ h, float* __restrict__ pooled) {
    int j = threadIdx.x & 127, p = threadIdx.x >> 7;
    float s = 0.f;
    for (int n = blockIdx.x * 2 + p; n < NN; n += 512) s += h[(size_t)n * HH + j];
    unsafeAtomicAdd(&pooled[j], s);
}

__global__ void final_k(const float* __restrict__ pooled, const float* __restrict__ Wout,
                        const float* __restrict__ bout, float* __restrict__ out) {
    int lane = threadIdx.x;
    float s = pooled[lane] * Wout[lane] + pooled[lane + 64] * Wout[lane + 64];
#pragma unroll
    for (int o = 32; o; o >>= 1) s += __shfl_xor(s, o);
    if (lane == 0) out[0] = s * (1.f / (float)NN) + bout[0];
}

// ---------------------------------------------------------------------------
extern "C" void kernel_launch(void* const* d_in, const int* in_sizes, int n_in,
                              void* d_out, int out_size, void* d_ws, size_t ws_size,
                              hipStream_t stream) {
    const float* lc   = (const float*)d_in[0];
    const int*   ei   = (const int*)d_in[1];
    const float* Wih0 = (const float*)d_in[2];
    const float* Whh0 = (const float*)d_in[3];
    const float* bih0 = (const float*)d_in[4];
    const float* bhh0 = (const float*)d_in[5];
    const float* Wih1 = (const float*)d_in[6];
    const float* Whh1 = (const float*)d_in[7];
    const float* bih1 = (const float*)d_in[8];
    const float* bhh1 = (const float*)d_in[9];
    const float* Wout = (const float*)d_in[22];
    const float* bout = (const float*)d_in[23];
    float* out = (float*)d_out;

    // workspace layout (~84 MB total); xT aliases hw+hacc (only live during LSTM)
    float* ws    = (float*)d_ws;
    float* h     = ws;                              // N*H
    float* hw    = h + (size_t)NN * HH;             // N*H
    float* hacc  = hw + (size_t)NN * HH;            // N*H
    float* xT    = hw;                              // T*N (fits in hw+hacc: 10e6 <= 12.8e6)
    float* enorm = hacc + (size_t)NN * HH;          // E
    float* deg   = enorm + EE;                      // N
    float* dinv  = deg + NN;                        // N
    float* b0g   = dinv + NN;                       // 512
    float* b1g   = b0g + 512;
    float* wxg   = b1g + 512;
    float* pooled = wxg + 512;                      // 128
    unsigned short* w0p  = (unsigned short*)(pooled + 128);  // 65536 each
    unsigned short* w1ip = w0p + 65536;
    unsigned short* w1hp = w1ip + 65536;

    pack_w<<<128, 64, 0, stream>>>(Whh0, w0p);
    pack_w<<<128, 64, 0, stream>>>(Wih1, w1ip);
    pack_w<<<128, 64, 0, stream>>>(Whh1, w1hp);
    bias_prep<<<2, 256, 0, stream>>>(bih0, bhh0, bih1, bhh1, Wih0, b0g, b1g, wxg);
    {
        dim3 g((TT + 31) / 32, (NN + 31) / 32), b(32, 8);
        transpose_lc<<<g, b, 0, stream>>>(lc, xT);
    }
    deg_init<<<(NN + 255) / 256, 256, 0, stream>>>(deg);
    deg_edges<<<(EE + 255) / 256, 256, 0, stream>>>(ei, deg);
    dinv_k<<<(NN + 255) / 256, 256, 0, stream>>>(deg, dinv);
    enorm_k<<<(EE + 255) / 256, 256, 0, stream>>>(ei, dinv, enorm);

    lstm_kernel<<<(NN + 63) / 64, 256, 0, stream>>>(xT, w0p, w1ip, w1hp, b0g, b1g, wxg, h);

    for (int l = 0; l < 3; ++l) {
        const float* Wg = (const float*)d_in[10 + 4 * l];
        const float* bg = (const float*)d_in[11 + 4 * l];
        const float* gm = (const float*)d_in[12 + 4 * l];
        const float* bt = (const float*)d_in[13 + 4 * l];
        gcn_gemm<<<(NN + 31) / 32, 256, 0, stream>>>(h, Wg, hw);
        gcn_init<<<(NN * 32 + 255) / 256, 256, 0, stream>>>(hw, dinv, bg, hacc);
        gcn_scatter<<<(EE * 32) / 256, 256, 0, stream>>>(hw, ei, enorm, hacc);
        gcn_ln<<<(NN + 3) / 4, 256, 0, stream>>>(hacc, gm, bt, h);
    }

    hipMemsetAsync(pooled, 0, HH * sizeof(float), stream);
    pool_k<<<256, 256, 0, stream>>>(h, pooled);
    final_k<<<1, 64, 0, stream>>>(pooled, Wout, bout, out);
}